// Round 3
// baseline (193.054 us; speedup 1.0000x reference)
//
#include <hip/hip_runtime.h>
#include <hip/hip_bf16.h>
#include <stdint.h>
#include <stddef.h>

#define B_ 8
#define S_ 2048
#define D_ 256
#define NROWS (B_ * S_)  // 16384

typedef __attribute__((ext_vector_type(8))) short short8;
typedef __attribute__((ext_vector_type(4))) short short4v;
typedef __attribute__((ext_vector_type(4))) float f32x4;

// round-to-nearest-even fp32 -> bf16 bit pattern
__device__ __forceinline__ short bf16of(float f) {
  union { float f; unsigned u; } x; x.f = f;
  unsigned r = x.u + 0x7FFFu + ((x.u >> 16) & 1u);
  return (short)(r >> 16);
}

// async global->LDS, 16B per lane (wave-uniform base + lane*16 layout)
__device__ __forceinline__ void async_ld16(const void* g, void* s) {
  __builtin_amdgcn_global_load_lds(
      (const __attribute__((address_space(1))) void*)g,
      (__attribute__((address_space(3))) void*)s, 16, 0, 0);
}

// ---- K_pre (merged): rows (hs/ds + bf16 casts) and U transpose ----
// grid 8256: [0,4096) head rows, [4096,8192) dep rows, [8192,8256) U-transpose
__global__ void k_pre(const float* __restrict__ head, const float* __restrict__ dep,
                      const float* __restrict__ U, const float* __restrict__ W,
                      float* __restrict__ hs, float* __restrict__ ds,
                      short* __restrict__ headB, short* __restrict__ depB,
                      short* __restrict__ UT) {
  const int bid = blockIdx.x;
  const int t = threadIdx.x;
  if (bid < 8192) {
    const float* X; const float* wv; float* sv; short* XB;
    if (bid < 4096) { X = head; wv = W;      sv = hs; XB = headB; }
    else            { X = dep;  wv = W + D_; sv = ds; XB = depB;  }
    const int row = (bid & 4095) * 4 + (t >> 6);
    const int l = t & 63;
    const float4 v  = *(const float4*)(X + (size_t)row * D_ + l * 4);
    const float4 wq = *(const float4*)(wv + l * 4);
    short4v pk;
    pk[0] = bf16of(v.x); pk[1] = bf16of(v.y); pk[2] = bf16of(v.z); pk[3] = bf16of(v.w);
    *(short4v*)(XB + (size_t)row * D_ + l * 4) = pk;
    float p = v.x * wq.x + v.y * wq.y + v.z * wq.z + v.w * wq.w;
    p += __shfl_xor(p, 1); p += __shfl_xor(p, 2); p += __shfl_xor(p, 4);
    p += __shfl_xor(p, 8); p += __shfl_xor(p, 16); p += __shfl_xor(p, 32);
    if (l == 0) sv[row] = p;
  } else {
    // UT[n][k] = bf16(U[k][n]); block handles 4 consecutive k rows
    const int k0 = (bid - 8192) * 4;
    const int n = t;
#pragma unroll
    for (int kk = 0; kk < 4; ++kk)
      UT[n * D_ + k0 + kk] = bf16of(U[(k0 + kk) * D_ + n]);
  }
}

// ---------------- K1: Ahat = headB @ U (bf16), all-async staging ----------------
// grid (2, 128): x = U-col tile (nbase), y = flat row tile (mbase)
__launch_bounds__(256, 2)
__global__ void k_ahat(const short* __restrict__ headB, const short* __restrict__ UT,
                       short* __restrict__ Ahat) {
  __shared__ __align__(16) short sU[4 * 128 * 32];  // 32 KB: U-cols (A-operand, m = n_col)
  __shared__ __align__(16) short sH[4 * 128 * 32];  // 32 KB: head rows (B-operand, n = i)
  const int t = threadIdx.x;
  const int w = t >> 6;
  const int l = t & 63;
  const int quad = l >> 4;
  const int nbase = blockIdx.x * 128;
  const int mbase = blockIdx.y * 128;

  f32x4 acc[4][4];
#pragma unroll
  for (int i = 0; i < 4; ++i)
#pragma unroll
    for (int j = 0; j < 4; ++j) acc[i][j] = (f32x4)0.0f;

  for (int it = 0; it < 2; ++it) {  // BK = 128
    __syncthreads();
#pragma unroll
    for (int kb = 0; kb < 4; ++kb) {
#pragma unroll
      for (int c = 0; c < 2; ++c) {
        int q = c * 256 + t;
        int r = q >> 2, qc = q & 3;
        int kk = it * 128 + kb * 32 + qc * 8;
        async_ld16(UT + (size_t)(nbase + r) * D_ + kk, (char*)sU + kb * 8192 + q * 16);
        async_ld16(headB + (size_t)(mbase + r) * D_ + kk, (char*)sH + kb * 8192 + q * 16);
      }
    }
    __syncthreads();
    const short8* pU = (const short8*)sU;
    const short8* pH = (const short8*)sH;
#pragma unroll
    for (int kb = 0; kb < 4; ++kb) {
      short8 aF[4], bF[4];
#pragma unroll
      for (int mt = 0; mt < 4; ++mt)
        aF[mt] = pU[(kb * 128 + (w >> 1) * 64 + mt * 16 + (l & 15)) * 4 + quad];
#pragma unroll
      for (int nt = 0; nt < 4; ++nt)
        bF[nt] = pH[(kb * 128 + (w & 1) * 64 + nt * 16 + (l & 15)) * 4 + quad];
#pragma unroll
      for (int mt = 0; mt < 4; ++mt)
#pragma unroll
        for (int nt = 0; nt < 4; ++nt)
          acc[mt][nt] = __builtin_amdgcn_mfma_f32_16x16x32_bf16(aF[mt], bF[nt], acc[mt][nt], 0, 0, 0);
    }
  }

  // D[m=n_col][n=i] -> lane holds 4 consecutive n_col for fixed i: short4 stores
#pragma unroll
  for (int mt = 0; mt < 4; ++mt) {
    int n_loc = (w >> 1) * 64 + mt * 16 + quad * 4;
#pragma unroll
    for (int nt = 0; nt < 4; ++nt) {
      int i_loc = (w & 1) * 64 + nt * 16 + (l & 15);
      short4v pk;
      pk[0] = bf16of(acc[mt][nt][0]); pk[1] = bf16of(acc[mt][nt][1]);
      pk[2] = bf16of(acc[mt][nt][2]); pk[3] = bf16of(acc[mt][nt][3]);
      *(short4v*)(Ahat + (size_t)(mbase + i_loc) * D_ + nbase + n_loc) = pk;
    }
  }
}

// ------- K2: out[b,i,o] = sum_k Ahat[b,i,k] depB[b,o,k] + hs[i] + ds[o] + bias -------
// Register-staged double-buffered pipeline: global->VGPR prefetch issued before
// MFMA, ds_write after — barrier never waits on in-flight global loads.
// grid (16 o-tiles, 16 i-tiles, 8 b); A-operand = depB (m = o), B-operand = Ahat (n = i)
__launch_bounds__(256, 2)
__global__ void k_main(const short* __restrict__ Ahat, const short* __restrict__ depB,
                       const float* __restrict__ hs, const float* __restrict__ ds,
                       const float* __restrict__ eb, float* __restrict__ out) {
  __shared__ __align__(16) short sA[2][2 * 128 * 32];  // [buf][kb*4096 + row*32 + k] 16 KB/buf
  __shared__ __align__(16) short sD[2][2 * 128 * 32];
  __shared__ float hs_s[128];
  __shared__ float ds_s[128];
  const int t = threadIdx.x;
  const int w = t >> 6;
  const int l = t & 63;
  const int quad = l >> 4;
  const int b = blockIdx.z;
  const int mbase = blockIdx.y * 128;  // i
  const int nbase = blockIdx.x * 128;  // o

  if (t < 128) hs_s[t] = hs[b * S_ + mbase + t];
  else         ds_s[t - 128] = ds[b * S_ + nbase + t - 128];

  f32x4 acc[4][4];
#pragma unroll
  for (int i = 0; i < 4; ++i)
#pragma unroll
    for (int j = 0; j < 4; ++j) acc[i][j] = (f32x4)0.0f;

  // Staging map (per operand, per BK=64 iter): thread t handles 4 chunks of 16 B:
  //   rows t>>3 + {0,32,64,96}, half = (t>>2)&1 (which 32-k slice), part = t&3
  const int row0 = t >> 3;
  const int half = (t >> 2) & 1;
  const int part = t & 3;
  const short* gA = Ahat + (size_t)(b * S_ + mbase) * D_ + half * 32 + part * 8;
  const short* gD = depB + (size_t)(b * S_ + nbase) * D_ + half * 32 + part * 8;
  const int ldsOff = half * 4096 + row0 * 32 + part * 8;  // shorts; +32c*32 per chunk

  float4 rA[4], rD[4];
  // prologue: load it=0 into regs, write buf0
#pragma unroll
  for (int c = 0; c < 4; ++c) {
    rA[c] = *(const float4*)(gA + (size_t)(row0 + 32 * c) * D_);
    rD[c] = *(const float4*)(gD + (size_t)(row0 + 32 * c) * D_);
  }
#pragma unroll
  for (int c = 0; c < 4; ++c) {
    *(float4*)((char*)&sA[0][0] + (ldsOff + c * 1024) * 2) = rA[c];
    *(float4*)((char*)&sD[0][0] + (ldsOff + c * 1024) * 2) = rD[c];
  }
  __syncthreads();

  for (int it = 0; it < 4; ++it) {
    const int p = it & 1;
    if (it < 3) {  // prefetch next K-slice into registers (in flight during MFMA)
#pragma unroll
      for (int c = 0; c < 4; ++c) {
        rA[c] = *(const float4*)(gA + (size_t)(row0 + 32 * c) * D_ + (it + 1) * 64);
        rD[c] = *(const float4*)(gD + (size_t)(row0 + 32 * c) * D_ + (it + 1) * 64);
      }
    }
    const short8* pA = (const short8*)sA[p];
    const short8* pD = (const short8*)sD[p];
#pragma unroll
    for (int kb = 0; kb < 2; ++kb) {
      short8 aF[4], bF[4];
#pragma unroll
      for (int mt = 0; mt < 4; ++mt)  // A-operand: dep rows (o)
        aF[mt] = pD[(kb * 128 + (w >> 1) * 64 + mt * 16 + (l & 15)) * 4 + quad];
#pragma unroll
      for (int nt = 0; nt < 4; ++nt)  // B-operand: Ahat rows (i)
        bF[nt] = pA[(kb * 128 + (w & 1) * 64 + nt * 16 + (l & 15)) * 4 + quad];
#pragma unroll
      for (int mt = 0; mt < 4; ++mt)
#pragma unroll
        for (int nt = 0; nt < 4; ++nt)
          acc[mt][nt] = __builtin_amdgcn_mfma_f32_16x16x32_bf16(aF[mt], bF[nt], acc[mt][nt], 0, 0, 0);
    }
    if (it < 3) {
#pragma unroll
      for (int c = 0; c < 4; ++c) {
        *(float4*)((char*)&sA[1 - p][0] + (ldsOff + c * 1024) * 2) = rA[c];
        *(float4*)((char*)&sD[1 - p][0] + (ldsOff + c * 1024) * 2) = rD[c];
      }
      __syncthreads();
    }
  }

  const float bias = eb[0];
#pragma unroll
  for (int mt = 0; mt < 4; ++mt) {
    int o_loc = (w >> 1) * 64 + mt * 16 + quad * 4;
    float4 dsv = *(const float4*)&ds_s[o_loc];
#pragma unroll
    for (int nt = 0; nt < 4; ++nt) {
      int i_loc = (w & 1) * 64 + nt * 16 + (l & 15);
      float hv = hs_s[i_loc] + bias;
      f32x4 a = acc[mt][nt];
      float4 o4;
      o4.x = a[0] + hv + dsv.x;
      o4.y = a[1] + hv + dsv.y;
      o4.z = a[2] + hv + dsv.z;
      o4.w = a[3] + hv + dsv.w;
      *(float4*)(out + (size_t)(b * S_ + mbase + i_loc) * S_ + nbase + o_loc) = o4;
    }
  }
}

extern "C" void kernel_launch(void* const* d_in, const int* in_sizes, int n_in,
                              void* d_out, int out_size, void* d_ws, size_t ws_size,
                              hipStream_t stream) {
  const float* head = (const float*)d_in[0];
  const float* dep  = (const float*)d_in[1];
  const float* U    = (const float*)d_in[2];
  const float* W    = (const float*)d_in[3];  // (1, 512): wh | wd
  const float* eb   = (const float*)d_in[4];
  float* out = (float*)d_out;

  char* ws = (char*)d_ws;
  short* UT    = (short*)ws;                       // 256*256*2     = 128 KB
  float* hs    = (float*)(ws + (128 << 10));       // 16384*4       = 64 KB
  float* ds    = (float*)(ws + (192 << 10));       // 16384*4       = 64 KB
  short* headB = (short*)(ws + (256 << 10));       // 16384*256*2   = 8 MB
  short* depB  = (short*)(ws + (256 << 10) + (8 << 20));
  short* Ahat  = (short*)(ws + (256 << 10) + (16 << 20));

  k_pre<<<dim3(8256), dim3(256), 0, stream>>>(head, dep, U, W, hs, ds, headB, depB, UT);
  k_ahat<<<dim3(2, 128), dim3(256), 0, stream>>>(headB, UT, Ahat);
  k_main<<<dim3(16, 16, 8), dim3(256), 0, stream>>>(Ahat, depB, hs, ds, eb, out);
}